// Round 5
// baseline (434.949 us; speedup 1.0000x reference)
//
#include <hip/hip_runtime.h>

// SNN LIF scan: T=1024, B=32, N=2048. EXACT sequential-in-T (spikes binary
// -> trajectory must be bit-exact -> no T-parallelization).
// R9/R10: R7 (deep VGPR prefetch) and R8 (decoupled writer waves, clause-
// pinned 32-deep load batches) BOTH land at ~417us = 977 cy/timestep = one
// HBM latency per timestep: the VGPR-load path is collapsing to ~2
// outstanding loads per wave no matter how the source pipelines it. Fix:
// take the compiler out of the load path entirely.
//   - __builtin_amdgcn_global_load_lds (width=4) into a per-wave PRIVATE
//     LDS ring: no destination VGPRs -> compiler emits ZERO vmcnt waits.
//   - hand-counted ledger, T4-style: per iter issue order is
//     [s_waitcnt vmcnt(46)] [ds_read slot u] [compute] [GLL pair u+D] [store u]
//     pair(u) (issued at iter u-D) has exactly 1 store + 3*(D-1) = 46 vmem
//     ops younger -> vmcnt(46) is exact; ~32 loads + ~15 stores per wave
//     stay in flight permanently (~24 KB/CU >> 10 KB Little's-law knee).
//   - ring = 32 slots, prefetch distance D=16: GLL targets slot (u+16)&31,
//     never the slot being ds_read this iter -> no LDS write race, no
//     lgkm stall in the loop.
//   - waves fully independent (private ring halves). No barriers at all.
// R10 = R9 resubmitted verbatim (R9 died to container-acquire infra
// failure before compile; hang-risk audit clean: counted waits are
// monotone, zero barriers, ring distance safe).
// d_out layout: spikes[T*B*N] ++ v_final[B*N] ++ i_final[B*N].

#define TT 1024
#define BN 65536           // B*N floats per timestep
#define BN2 (BN / 2)       // v2f per timestep
#define D  16              // prefetch distance (timesteps)
#define RS 32              // ring slots = 2*D

typedef float v2f __attribute__((ext_vector_type(2)));
typedef __attribute__((address_space(3))) float* lds_fp;
typedef const __attribute__((address_space(1))) float* glb_fp;

__global__ __launch_bounds__(128, 1) void snn_lif_kernel(
    const float* __restrict__ xf,
    float* __restrict__ outf)
{
    // ring[wave][slot][128 floats] : 2*32*512 B = 32 KB, per-wave private.
    __shared__ float ring[2][RS][128];

    const int tid  = threadIdx.x;
    const int lane = tid & 63;
    const int wid  = tid >> 6;                    // 0 or 1
    const int idx  = blockIdx.x * 128 + tid;      // v2f lane id 0..32767

    // This wave's 512 B chunk of slab t: floats [blk*256 + wid*128 .. +128).
    const float* gw = xf + (size_t)blockIdx.x * 256 + wid * 128 + lane;
    v2f* __restrict__ sp = (v2f*)outf + idx;

    float v0 = 0.0f, v1 = 0.0f, i0 = 0.0f, i1 = 0.0f;
    const float c_mem = 0.1f;   // fp32(DT*TAU_MEM_INV)
    const float c_syn = 0.8f;   // fp32(1 - DT*TAU_SYN_INV)

    // Exact ref op sequence; _rn intrinsics forbid FMA contraction (spike
    // decisions are binary -- must match fp32 reference bit-exactly;
    // load-bearing, do not touch).
    auto step = [&](float& v, float& i, float xin) -> float {
        float dv    = __fmul_rn(c_mem, __fadd_rn(__fsub_rn(0.0f, v), i));
        float v_dec = __fadd_rn(v, dv);
        float i_dec = __fmul_rn(i, c_syn);
        bool fired  = (v_dec > 1.0f);
        v = fired ? 0.0f : v_dec;
        i = __fadd_rn(i_dec, xin);
        return fired ? 1.0f : 0.0f;
    };

    // Prologue: slabs 0..D-1 into slots 0..D-1 (2 GLL per slab: lanes load
    // floats [0..63] and [64..127] of this wave's chunk; LDS dest is the
    // wave-uniform base, HW adds lane*4).
    #pragma unroll
    for (int u = 0; u < D; ++u) {
        const float* g = gw + (size_t)u * BN;
        __builtin_amdgcn_global_load_lds((glb_fp)g,
                                         (lds_fp)&ring[wid][u][0], 4, 0, 0);
        __builtin_amdgcn_global_load_lds((glb_fp)(g + 64),
                                         (lds_fp)&ring[wid][u][64], 4, 0, 0);
    }
    asm volatile("s_waitcnt vmcnt(0)" ::: "memory");   // one-time drain

    #pragma unroll 1
    for (int u = 0; u < TT - D; ++u) {
        // Counted wait: guarantees GLL pair for slab u has retired while
        // leaving the newest 46 vmem ops (15 future pairs + stores) in
        // flight. Exact from iter D on; vacuously true before that.
        asm volatile("s_waitcnt vmcnt(46)" ::: "memory");
        __builtin_amdgcn_sched_barrier(0);

        v2f x = ((v2f*)&ring[wid][u & (RS - 1)][0])[lane];   // ds_read_b64
        v2f z;
        z.x = step(v0, i0, x.x);
        z.y = step(v1, i1, x.y);

        // Prefetch slab u+D into slot (u+D)&31 (never the slot read above).
        const float* g = gw + (size_t)(u + D) * BN;
        __builtin_amdgcn_global_load_lds((glb_fp)g,
                                         (lds_fp)&ring[wid][(u + D) & (RS - 1)][0], 4, 0, 0);
        __builtin_amdgcn_global_load_lds((glb_fp)(g + 64),
                                         (lds_fp)&ring[wid][(u + D) & (RS - 1)][64], 4, 0, 0);

        __builtin_nontemporal_store(z, &sp[(size_t)u * BN2]);
    }

    asm volatile("s_waitcnt vmcnt(0)" ::: "memory");   // tail drain, once

    #pragma unroll 1
    for (int u = TT - D; u < TT; ++u) {
        v2f x = ((v2f*)&ring[wid][u & (RS - 1)][0])[lane];
        v2f z;
        z.x = step(v0, i0, x.x);
        z.y = step(v1, i1, x.y);
        __builtin_nontemporal_store(z, &sp[(size_t)u * BN2]);
    }

    // Final state (v2f contiguous in both v and i regions).
    v2f* vf  = (v2f*)(outf + (size_t)TT * BN) + idx;
    v2f* iff = (v2f*)(outf + (size_t)TT * BN + BN) + idx;
    v2f a; a.x = v0; a.y = v1; *vf = a;
    v2f b; b.x = i0; b.y = i1; *iff = b;
}

extern "C" void kernel_launch(void* const* d_in, const int* in_sizes, int n_in,
                              void* d_out, int out_size, void* d_ws, size_t ws_size,
                              hipStream_t stream) {
    const float* x = (const float*)d_in[0];
    float* out = (float*)d_out;
    // 256 blocks x 128 threads: 1 block/CU, 2 independent waves/CU.
    snn_lif_kernel<<<BN2 / 128, 128, 0, stream>>>(x, out);
}

// Round 6
// 414.571 us; speedup vs baseline: 1.0492x; 1.0492x over previous
//
#include <hip/hip_runtime.h>

// SNN LIF scan: T=1024, B=32, N=2048. EXACT sequential-in-T (spikes binary
// -> trajectory must be bit-exact -> no T-parallelization).
// R11: R7 (46-deep VGPR prefetch), R8 (decoupled writer waves), R10
// (global_load_lds ring + hand-counted vmcnt ledger, ~24KB/wave provably in
// flight) ALL land at 417-435us = ~984 cy/timestep. Per-wave MLP is NOT the
// limiter: the memory system serves ~2.5 GB/s per wave for this pattern no
// matter how many requests are outstanding (per-wave in-flight line budget
// ~8 lines ~= 2.7 GB/s/wave at 900cy — matches). Cross-check: fillBuffer
// ~8 GB/s/wave (pure store), m13 copy ~3 GB/s/wave at 8+ waves/CU. The only
// scaling axis left is WAVE COUNT — constant at 512 (2/CU) since R5.
// This round: one neuron per thread -> 65536 threads = 1024 waves = 4/CU,
// doubling independent request streams per CU. Structure is R7's proven
// simple deep-prefetch loop (U=16 double-batch, nt loads+stores); R8/R10
// showed fancier store handling is neutral at equal wave count.
// d_out layout: spikes[T*B*N] ++ v_final[B*N] ++ i_final[B*N].

#define TT 1024
#define BN 65536           // B*N floats per timestep
#define U  16              // scalar batch per pipeline phase (2 phases)

__global__ __launch_bounds__(256, 1) void snn_lif_kernel(
    const float* __restrict__ xf,
    float* __restrict__ outf)
{
    const int idx = blockIdx.x * 256 + threadIdx.x;       // 0..BN-1 (neuron)
    const float* __restrict__ xp = xf + idx;
    float* __restrict__ sp = outf + idx;

    float v = 0.0f, i = 0.0f;

    const float c_mem = 0.1f;   // fp32(DT*TAU_MEM_INV)
    const float c_syn = 0.8f;   // fp32(1 - DT*TAU_SYN_INV)

    // One LIF step. Exact ref op sequence; _rn intrinsics forbid FMA
    // contraction (spike decisions are binary -- must match the fp32
    // reference bit-exactly; load-bearing, do not touch).
    auto step = [&](float xin) -> float {
        float dv    = __fmul_rn(c_mem, __fadd_rn(__fsub_rn(0.0f, v), i));
        float v_dec = __fadd_rn(v, dv);
        float i_dec = __fmul_rn(i, c_syn);
        bool fired  = (v_dec > 1.0f);
        v = fired ? 0.0f : v_dec;
        i = __fadd_rn(i_dec, xin);
        return fired ? 1.0f : 0.0f;
    };

    float xa[U], xb[U];

    // Prologue: batch A in flight.
    #pragma unroll
    for (int k = 0; k < U; ++k)
        xa[k] = __builtin_nontemporal_load(&xp[(size_t)k * BN]);

    #pragma unroll 1
    for (int t0 = 0; t0 < TT; t0 += 2 * U) {
        // Issue batch B before consuming batch A.
        #pragma unroll
        for (int k = 0; k < U; ++k)
            xb[k] = __builtin_nontemporal_load(&xp[(size_t)(t0 + U + k) * BN]);

        #pragma unroll
        for (int k = 0; k < U; ++k) {
            float z = step(xa[k]);
            __builtin_nontemporal_store(z, &sp[(size_t)(t0 + k) * BN]);
        }

        // Refill batch A for the next outer iteration (uniform branch).
        if (t0 + 2 * U < TT) {
            #pragma unroll
            for (int k = 0; k < U; ++k)
                xa[k] = __builtin_nontemporal_load(
                    &xp[(size_t)(t0 + 2 * U + k) * BN]);
        }

        #pragma unroll
        for (int k = 0; k < U; ++k) {
            float z = step(xb[k]);
            __builtin_nontemporal_store(z, &sp[(size_t)(t0 + U + k) * BN]);
        }
    }

    // Final state.
    outf[(size_t)TT * BN + idx] = v;
    outf[(size_t)TT * BN + BN + idx] = i;
}

extern "C" void kernel_launch(void* const* d_in, const int* in_sizes, int n_in,
                              void* d_out, int out_size, void* d_ws, size_t ws_size,
                              hipStream_t stream) {
    const float* x = (const float*)d_in[0];
    float* out = (float*)d_out;
    // 65536 threads: 256 blocks x 256 -> 1 block/CU, 4 waves/CU (2x R5-R10).
    snn_lif_kernel<<<BN / 256, 256, 0, stream>>>(x, out);
}